// Round 2
// baseline (416.711 us; speedup 1.0000x reference)
//
#include <hip/hip_runtime.h>
#include <hip/hip_fp16.h>
#include <climits>
#include <math.h>

#define Bc   2
#define Tc   2048
#define Dc   2048
#define Nc   16
#define KHc  8
#define Hc   128
#define Sc   2048

constexpr float EPSc   = 1e-6f;
constexpr float SCALE2 = 0.1275174477984469f;     // (1/sqrt(128)) * log2(e)

typedef short short8 __attribute__((ext_vector_type(8)));
typedef _Float16 half8 __attribute__((ext_vector_type(8)));
typedef __fp16 fp16x2 __attribute__((ext_vector_type(2)));
typedef float float4v __attribute__((ext_vector_type(4)));

union U16x8 { uint4 u; short8 s8; half8 h8; unsigned short us[8]; };
union H2U  { fp16x2 h; unsigned u; };
union S8H8 { short8 s; half8 h; };

__device__ __forceinline__ unsigned short f2bf(float f) {
    union { float f; unsigned u; } v; v.f = f;
    unsigned r = v.u + 0x7FFFu + ((v.u >> 16) & 1u);
    return (unsigned short)(r >> 16);
}
__device__ __forceinline__ float bf2f(unsigned short u) {
    union { unsigned u; float f; } v; v.u = ((unsigned)u) << 16;
    return v.f;
}

// ---------------------------------------------------------------------------
// prep: fused meta + x-cast + 4 weight transposes (12 launches -> 1)
// ---------------------------------------------------------------------------
__device__ __forceinline__ void tc_body(const float* __restrict__ in,
                                        unsigned short* __restrict__ out,
                                        int R, int C, int bx, int by, int tid,
                                        float tile[32][33])
{
    int c0 = bx * 32, r0 = by * 32;
#pragma unroll
    for (int i = 0; i < 4; ++i) {
        int row = (tid >> 5) + i * 8, col = tid & 31;
        tile[row][col] = in[(size_t)(r0 + row) * C + c0 + col];
    }
    __syncthreads();
#pragma unroll
    for (int i = 0; i < 4; ++i) {
        int rowo = (tid >> 5) + i * 8, colo = tid & 31;
        out[(size_t)(c0 + rowo) * R + r0 + colo] = f2bf(tile[colo][rowo]);
    }
}

__global__ __launch_bounds__(256) void prep(const float* __restrict__ x,
                                            const float* __restrict__ qw,
                                            const float* __restrict__ kw,
                                            const float* __restrict__ vw,
                                            const float* __restrict__ ow,
                                            const int* __restrict__ seg,
                                            const int* __restrict__ start_ind,
                                            int* __restrict__ meta,
                                            unsigned short* __restrict__ xb,
                                            unsigned short* __restrict__ qkvwT,
                                            unsigned short* __restrict__ owT)
{
    __shared__ float tile[32][33];
    __shared__ int s_max, s_amax, s_nz;
    int id = blockIdx.x;
    int tid = threadIdx.x;

    if (id < Bc) {   // meta
        int b = id;
        if (tid == 0) { s_max = INT_MIN; s_amax = Tc; s_nz = Tc; }
        __syncthreads();
        int lmax = INT_MIN;
        for (int t = tid; t < Tc; t += 256) lmax = max(lmax, seg[b * Tc + t]);
        atomicMax(&s_max, lmax);
        __syncthreads();
        int mv = s_max;
        int lamax = Tc, lnz = Tc;
        for (int t = tid; t < Tc; t += 256) {
            int v = seg[b * Tc + t];
            if (v == mv) lamax = min(lamax, t);
            if (v != 0)  lnz   = min(lnz, t);
        }
        atomicMin(&s_amax, lamax);
        atomicMin(&s_nz, lnz);
        __syncthreads();
        if (tid == 0) {
            meta[b] = s_amax;
            int st = start_ind[b];
            meta[Bc + b] = (st < 0) ? s_nz : st;
        }
        return;
    }
    id -= Bc;
    if (id < 4096) {   // cast x
        size_t base = ((size_t)id * 256 + tid) * 8;
        float4 a = *(const float4*)&x[base];
        float4 b = *(const float4*)&x[base + 4];
        U16x8 o;
        o.us[0] = f2bf(a.x); o.us[1] = f2bf(a.y); o.us[2] = f2bf(a.z); o.us[3] = f2bf(a.w);
        o.us[4] = f2bf(b.x); o.us[5] = f2bf(b.y); o.us[6] = f2bf(b.z); o.us[7] = f2bf(b.w);
        *(uint4*)&xb[base] = o.u;
        return;
    }
    id -= 4096;
    if (id < 4096) { tc_body(qw, qkvwT, 2048, 2048, id & 63, id >> 6, tid, tile); return; }
    id -= 4096;
    if (id < 2048) { tc_body(kw, qkvwT + (size_t)2048 * 2048, 2048, 1024, id & 31, id >> 5, tid, tile); return; }
    id -= 2048;
    if (id < 2048) { tc_body(vw, qkvwT + (size_t)3072 * 2048, 2048, 1024, id & 31, id >> 5, tid, tile); return; }
    id -= 2048;
    tc_body(ow, owT, 2048, 2048, id & 63, id >> 6, tid, tile);
}

// ---------------------------------------------------------------------------
// bf16 MFMA GEMM (m97 structure): C[M,N] = A[M,K] * BT[N,K]^T.
// ---------------------------------------------------------------------------
__global__ __launch_bounds__(256, 2) void gemm_mfma(const unsigned short* __restrict__ A,
                                                    const unsigned short* __restrict__ BT,
                                                    void* __restrict__ Cout,
                                                    int M, int N, int K, int out_fp32)
{
    __shared__ __align__(16) unsigned short As[128 * 32];
    __shared__ __align__(16) unsigned short Bs[128 * 32];
    int tid = threadIdx.x;
    int lane = tid & 63, w = tid >> 6;
    int quad = lane >> 4, l15 = lane & 15;
    int bm = blockIdx.y * 128, bn = blockIdx.x * 128;
    int wm = (w >> 1) * 64, wn = (w & 1) * 64;

    int srow = lane >> 2;
    int pl   = lane & 3;
    int sw   = (quad ^ ((l15 >> 1) & 3)) * 8;

    float4v acc[16];
#pragma unroll
    for (int i = 0; i < 16; ++i) acc[i] = (float4v)0.f;

    for (int k0 = 0; k0 < K; k0 += 32) {
        __syncthreads();
#pragma unroll
        for (int c = 0; c < 2; ++c) {
            int j = w * 2 + c;
            int row = j * 16 + srow;
            int pg = pl ^ ((row >> 1) & 3);
            __builtin_amdgcn_global_load_lds(
                (__attribute__((address_space(1))) void*)(A + (size_t)(bm + row) * K + k0 + pg * 8),
                (__attribute__((address_space(3))) void*)(As + j * 512), 16, 0, 0);
            __builtin_amdgcn_global_load_lds(
                (__attribute__((address_space(1))) void*)(BT + (size_t)(bn + row) * K + k0 + pg * 8),
                (__attribute__((address_space(3))) void*)(Bs + j * 512), 16, 0, 0);
        }
        __syncthreads();
        short8 af[4];
#pragma unroll
        for (int mi = 0; mi < 4; ++mi)
            af[mi] = *(const short8*)&As[(wm + mi * 16 + l15) * 32 + sw];
#pragma unroll
        for (int ni = 0; ni < 4; ++ni) {
            short8 bf = *(const short8*)&Bs[(wn + ni * 16 + l15) * 32 + sw];
#pragma unroll
            for (int mi = 0; mi < 4; ++mi)
                acc[mi * 4 + ni] = __builtin_amdgcn_mfma_f32_16x16x32_bf16(af[mi], bf, acc[mi * 4 + ni], 0, 0, 0);
        }
    }

#pragma unroll
    for (int mi = 0; mi < 4; ++mi)
#pragma unroll
        for (int ni = 0; ni < 4; ++ni)
#pragma unroll
            for (int reg = 0; reg < 4; ++reg) {
                int row = bm + wm + mi * 16 + quad * 4 + reg;
                int col = bn + wn + ni * 16 + l15;
                float v = acc[mi * 4 + ni][reg];
                if (out_fp32) ((float*)Cout)[(size_t)row * N + col] = v;
                else ((unsigned short*)Cout)[(size_t)row * N + col] = f2bf(v);
            }
}

// ---------------------------------------------------------------------------
// post: fused norm_rope (Q in-place, K -> Kall) + K-cache fill + V transpose
// ---------------------------------------------------------------------------
__global__ __launch_bounds__(256) void post(unsigned short* __restrict__ QKVh,
                                            unsigned short* __restrict__ Kall,
                                            unsigned short* __restrict__ Vt,
                                            const float* __restrict__ qw,
                                            const float* __restrict__ kw,
                                            const int* __restrict__ seg,
                                            const int* __restrict__ meta,
                                            const int* __restrict__ cur_ptr,
                                            const float* __restrict__ kc,
                                            const float* __restrict__ vc)
{
    int id = blockIdx.x;
    int tid = threadIdx.x;
    int cur = cur_ptr[0];

    if (id < 24576) {   // norm + rope
        int rowid = id * 4 + (tid >> 6);
        int lane = tid & 63;
        int hh = rowid % 24;
        int bt = rowid / 24;
        int t = bt & (Tc - 1);
        int b = bt >> 11;

        const unsigned short* in;
        unsigned short* out;
        const float* wt;
        if (hh < 16) {
            unsigned short* p = QKVh + (size_t)bt * 4096 + hh * Hc;
            in = p; out = p; wt = qw;
        } else {
            int kh = hh - 16;
            in = QKVh + (size_t)bt * 4096 + 2048 + kh * Hc;
            out = Kall + (((size_t)b * Sc + cur + t) * KHc + kh) * Hc;
            wt = kw;
        }
        float v1 = bf2f(in[lane]), v2 = bf2f(in[lane + 64]);
        float ssq = v1 * v1 + v2 * v2;
#pragma unroll
        for (int off = 1; off < 64; off <<= 1) ssq += __shfl_xor(ssq, off);
        float rinv = rsqrtf(ssq * (1.0f / Hc) + EPSc);

        int sg = seg[bt];
        long long pos = (sg != 0) ? (long long)(t - meta[b]) : (long long)(1 << 30);
        float posf = (float)(pos + (long long)cur);
        float inv_freq = exp2f(-(float)lane * (19.931568569324174f / 64.0f));
        float s, c;
        sincosf(posf * inv_freq, &s, &c);

        float n1 = wt[lane] * v1 * rinv;
        float n2 = wt[lane + 64] * v2 * rinv;
        out[lane]      = f2bf(n1 * c - n2 * s);
        out[lane + 64] = f2bf(n2 * c + n1 * s);
        return;
    }
    id -= 24576;
    if (id < 2048) {   // K cache fill
        size_t base = ((size_t)id * 256 + tid) * 8;
        int s = (int)((base >> 10) & (Sc - 1));
        if (s >= cur && s < cur + Tc) return;
        float4 a = *(const float4*)&kc[base];
        float4 b = *(const float4*)&kc[base + 4];
        U16x8 o;
        o.us[0] = f2bf(a.x); o.us[1] = f2bf(a.y); o.us[2] = f2bf(a.z); o.us[3] = f2bf(a.w);
        o.us[4] = f2bf(b.x); o.us[5] = f2bf(b.y); o.us[6] = f2bf(b.z); o.us[7] = f2bf(b.w);
        *(uint4*)&Kall[base] = o.u;
        return;
    }
    id -= 2048;
    {   // V transpose -> f16
        int gid = id * 256 + tid;
        int h  = gid & 127;
        int s8 = ((gid >> 7) & 255) * 8;
        int kh = (gid >> 15) & 7;
        int b  = gid >> 18;
        int curT = cur + Tc;
        unsigned short tmp[8];
#pragma unroll
        for (int e = 0; e < 8; ++e) {
            int s = s8 + e;
            float f;
            if (s >= cur && s < curT)
                f = bf2f(QKVh[(size_t)(b * Tc + (s - cur)) * 4096 + 3072 + kh * Hc + h]);
            else
                f = vc[((size_t)(b * Sc + s) * KHc + kh) * Hc + h];
            tmp[e] = __half_as_ushort(__float2half(f));
        }
        *(uint4*)&Vt[(((size_t)b * KHc + kh) * Hc + h) * Sc + s8] = *(uint4*)tmp;
    }
}

// ---------------------------------------------------------------------------
// MFMA flash attention, S^T formulation — TLP version:
//   64-row q-tiles, 128-thread blocks (2 waves), grid 1024 = 4 blocks/CU
//   (all co-resident, 2 waves/SIMD sustained). Single-buffered K/V LDS
//   (dbuf proven neutral in R1); inter-block TLP hides staging latency.
//   LDS = 16K (Ks) + 16K (Vs) + 8K (Ps) = 40960 B exactly -> 4 blocks/CU.
//   Balanced qt mapping: CU-slot group {bid, +256, +512, +768} gets
//   qt = {u, 15-u, 16+u, 31-u} -> constant 66 chunk-units per CU.
// ---------------------------------------------------------------------------
__global__ __launch_bounds__(128) void flash_mfma(const unsigned short* __restrict__ Qb,
                                                  const unsigned short* __restrict__ Kall,
                                                  const unsigned short* __restrict__ Vt,
                                                  const int* __restrict__ seg,
                                                  const int* __restrict__ meta,
                                                  const int* __restrict__ cur_ptr,
                                                  unsigned short* __restrict__ Ob)
{
    __shared__ __align__(16) unsigned short Ks[64 * 128];   // bf16 [s][h], swizzled
    __shared__ __align__(16) unsigned short Vs[128 * 64];   // f16  [h][s], swizzled
    __shared__ __align__(16) unsigned short Ps[64 * 64];    // f16  [q][s], XOR-swizzled

    int tid = threadIdx.x;
    int lane = tid & 63, w = tid >> 6;          // w in {0,1}
    int quad = lane >> 4, l15 = lane & 15;
    int bid = blockIdx.x;

    // balanced tile mapping
    int k4 = bid >> 8;           // 0..3  (CU round)
    int u  = (bid >> 5) & 7;     // 0..7
    int bn = bid & 31;
    int qt;
    if      (k4 == 0) qt = u;
    else if (k4 == 1) qt = 15 - u;
    else if (k4 == 2) qt = 16 + u;
    else              qt = 31 - u;
    int b = bn >> 4;
    int n = bn & 15;
    int kh = n >> 1;
    int cur = cur_ptr[0];
    int startb = meta[Bc + b];
    int curT = cur + Tc;
    int t0 = qt * 64 + w * 32;

    // Q fragments (B-operand layout == A layout: l15 -> q, quad*8+j -> h)
    short8 qf[2][4];
#pragma unroll
    for (int qtile = 0; qtile < 2; ++qtile)
#pragma unroll
        for (int ks = 0; ks < 4; ++ks) {
            int row = t0 + qtile * 16 + l15;
            U16x8 uq;
            uq.u = *(const uint4*)&Qb[(size_t)(b * Tc + row) * 4096 + n * Hc + ks * 32 + quad * 8];
            qf[qtile][ks] = uq.s8;
        }

    // per-lane mask metadata (q = l15-indexed)
    int ctq[2], clsq[2];
#pragma unroll
    for (int qtile = 0; qtile < 2; ++qtile) {
        int trow = t0 + qtile * 16 + l15;
        int sg = seg[b * Tc + trow];
        clsq[qtile] = (sg == 0) ? 0 : ((sg == 1) ? 1 : 2);
        ctq[qtile] = cur + trow;
    }
    unsigned long long m0 = __ballot(clsq[0] == 1);
    unsigned long long m1 = __ballot(clsq[1] == 1);
    bool allseg1 = ((m0 & m1) == 0xFFFFFFFFFFFFFFFFull);

    float lsum[2] = {0.f, 0.f};
    float4v oT[16];   // [htile][qtile] -> htile*2+qtile
#pragma unroll
    for (int i = 0; i < 16; ++i) oT[i] = (float4v)0.f;

    int s_end = min(Sc, cur + qt * 64 + 64);
    int nch = (s_end + 63) >> 6;

    // staging geometry (per wave: 8 K + 8 V global_load_lds per chunk)
    const size_t kstride = (size_t)KHc * Hc;
    const unsigned short* kptr[8];
    unsigned short* kdst[8];
#pragma unroll
    for (int i = 0; i < 8; ++i) {
        int j = w * 8 + i;                       // 0..15
        int row = j * 4 + (lane >> 4);           // 0..63
        int pl = lane & 15;
        int pg = pl ^ ((row >> 1) & 7);
        kptr[i] = Kall + (size_t)b * Sc * kstride + (size_t)row * kstride + kh * Hc + pg * 8;
        kdst[i] = Ks + j * 512;
    }
    const unsigned short* vptr[8];
    unsigned short* vdst[8];
#pragma unroll
    for (int i = 0; i < 8; ++i) {
        int j = w * 8 + i;                       // 0..15
        int h = j * 8 + (lane >> 3);             // 0..127
        int pl = lane & 7;
        int pg = pl ^ ((h >> 1) & 7);
        vptr[i] = Vt + ((size_t)b * KHc + kh) * (size_t)Hc * Sc + (size_t)h * Sc + pg * 8;
        vdst[i] = Vs + j * 512;
    }
    int sw3 = (l15 >> 1) & 7;
    int sw8 = l15 & 7;                           // Ps 16B-slot swizzle key (== row&7)
    unsigned short* psrow0 = Ps + (w * 32 + l15) * 64;          // qtile 0 row
    unsigned short* psrow1 = Ps + (w * 32 + 16 + l15) * 64;     // qtile 1 row

    for (int c = 0; c < nch; ++c) {
        int s0 = c * 64;
#pragma unroll
        for (int i = 0; i < 8; ++i) {
            __builtin_amdgcn_global_load_lds(
                (__attribute__((address_space(1))) void*)(kptr[i] + (size_t)s0 * kstride),
                (__attribute__((address_space(3))) void*)kdst[i], 16, 0, 0);
            __builtin_amdgcn_global_load_lds(
                (__attribute__((address_space(1))) void*)(vptr[i] + s0),
                (__attribute__((address_space(3))) void*)vdst[i], 16, 0, 0);
        }
        __syncthreads();

        // S^T = K·Q^T : st[stile][qtile], row=s, col=q
        float4v st[4][2];
#pragma unroll
        for (int i = 0; i < 4; ++i) { st[i][0] = (float4v)0.f; st[i][1] = (float4v)0.f; }
        __builtin_amdgcn_s_setprio(1);
#pragma unroll
        for (int ks = 0; ks < 4; ++ks) {
#pragma unroll
            for (int stile = 0; stile < 4; ++stile) {
                short8 kf = *(const short8*)&Ks[(stile * 16 + l15) * 128 + ((ks * 4 + quad) ^ sw3) * 8];
                st[stile][0] = __builtin_amdgcn_mfma_f32_16x16x32_bf16(kf, qf[0][ks], st[stile][0], 0, 0, 0);
                st[stile][1] = __builtin_amdgcn_mfma_f32_16x16x32_bf16(kf, qf[1][ks], st[stile][1], 0, 0, 0);
            }
        }
        __builtin_amdgcn_s_setprio(0);

        bool fullok = allseg1 && (s0 >= startb) && (s0 + 63 <= cur + t0) && (s0 + 63 < curT);

        // softmax: p = exp2(score*SCALE2); pack 4 s-consecutive f16 -> b64 store
#pragma unroll
        for (int stile = 0; stile < 4; ++stile) {
#pragma unroll
            for (int qtile = 0; qtile < 2; ++qtile) {
                float p0, p1, p2, p3;
                if (fullok) {
                    p0 = exp2f(st[stile][qtile][0] * SCALE2);
                    p1 = exp2f(st[stile][qtile][1] * SCALE2);
                    p2 = exp2f(st[stile][qtile][2] * SCALE2);
                    p3 = exp2f(st[stile][qtile][3] * SCALE2);
                } else {
                    int ctv = ctq[qtile], clsv = clsq[qtile];
                    float pp[4];
#pragma unroll
                    for (int reg = 0; reg < 4; ++reg) {
                        int s = s0 + stile * 16 + quad * 4 + reg;
                        int kvseg = (s >= startb && s < curT) ? 1 : 0;
                        bool ok = (s <= ctv) && (clsv == kvseg);
                        pp[reg] = exp2f(ok ? st[stile][qtile][reg] * SCALE2 : -1e30f);
                    }
                    p0 = pp[0]; p1 = pp[1]; p2 = pp[2]; p3 = pp[3];
                }
                lsum[qtile] += (p0 + p1) + (p2 + p3);
                H2U a, d;
                a.h = __builtin_amdgcn_cvt_pkrtz(p0, p1);
                d.h = __builtin_amdgcn_cvt_pkrtz(p2, p3);
                uint2 pk; pk.x = a.u; pk.y = d.u;
                unsigned short* pr = (qtile == 0) ? psrow0 : psrow1;
                // 16B slot = (stile*2 + (quad>>1)) ^ sw8 ; uint2 in half (quad&1)
                *(uint2*)&pr[(((stile * 2 + (quad >> 1)) ^ sw8) << 3) + (quad & 1) * 4] = pk;
            }
        }

        // O^T += V^T · P^T   (A = Vs f16, B = Ps f16) — own wave's Ps rows only
        __builtin_amdgcn_s_setprio(1);
#pragma unroll
        for (int kk = 0; kk < 2; ++kk) {
            S8H8 pf0, pf1;
            pf0.s = *(const short8*)&psrow0[((kk * 4 + quad) ^ sw8) << 3];
            pf1.s = *(const short8*)&psrow1[((kk * 4 + quad) ^ sw8) << 3];
#pragma unroll
            for (int htile = 0; htile < 8; ++htile) {
                S8H8 vf;
                vf.s = *(const short8*)&Vs[(htile * 16 + l15) * 64 + ((kk * 4 + quad) ^ sw3) * 8];
                oT[htile * 2 + 0] = __builtin_amdgcn_mfma_f32_16x16x32_f16(vf.h, pf0.h, oT[htile * 2 + 0], 0, 0, 0);
                oT[htile * 2 + 1] = __builtin_amdgcn_mfma_f32_16x16x32_f16(vf.h, pf1.h, oT[htile * 2 + 1], 0, 0, 0);
            }
        }
        __builtin_amdgcn_s_setprio(0);

        __syncthreads();   // WAR: next staging overwrites Ks/Vs
    }

    // l: sum across the 4 quads holding the same q (xor 16, 32)
    float linv[2];
#pragma unroll
    for (int qtile = 0; qtile < 2; ++qtile) {
        float l = lsum[qtile];
        l += __shfl_xor(l, 16);
        l += __shfl_xor(l, 32);
        linv[qtile] = (l > 0.f) ? (1.0f / l) : 0.f;
    }

    // epilogue: O^T col=q(l15), row=h(quad*4+reg) -> packed b64 bf16 stores
#pragma unroll
    for (int qtile = 0; qtile < 2; ++qtile) {
        int trow = t0 + qtile * 16 + l15;
        size_t base = ((size_t)(b * Tc + trow) * Nc + n) * Hc;
#pragma unroll
        for (int htile = 0; htile < 8; ++htile) {
            float4v v = oT[htile * 2 + qtile];
            unsigned short r0 = f2bf(v[0] * linv[qtile]);
            unsigned short r1 = f2bf(v[1] * linv[qtile]);
            unsigned short r2 = f2bf(v[2] * linv[qtile]);
            unsigned short r3 = f2bf(v[3] * linv[qtile]);
            uint2 pk;
            pk.x = (unsigned)r0 | ((unsigned)r1 << 16);
            pk.y = (unsigned)r2 | ((unsigned)r3 << 16);
            *(uint2*)&Ob[base + htile * 16 + quad * 4] = pk;
        }
    }
}

// ---------------------------------------------------------------------------
extern "C" void kernel_launch(void* const* d_in, const int* in_sizes, int n_in,
                              void* d_out, int out_size, void* d_ws, size_t ws_size,
                              hipStream_t stream)
{
    const float* x        = (const float*)d_in[0];
    const float* q_w      = (const float*)d_in[1];
    const float* k_w      = (const float*)d_in[2];
    const float* v_w      = (const float*)d_in[3];
    const float* o_w      = (const float*)d_in[4];
    const float* q_norm_w = (const float*)d_in[5];
    const float* k_norm_w = (const float*)d_in[6];
    const float* k_cache  = (const float*)d_in[7];
    const float* v_cache  = (const float*)d_in[8];
    const int*   seg      = (const int*)d_in[9];
    const int*   startind = (const int*)d_in[10];
    const int*   cur_ptr  = (const int*)d_in[11];
    (void)in_sizes; (void)n_in; (void)out_size; (void)ws_size;

    char* base = (char*)d_ws;
    int* meta = (int*)base;                                          //      1024 B
    unsigned short* QKVh = (unsigned short*)(base + 1024);           // 33.55 MB [4096][4096]
    unsigned short* Kall = (unsigned short*)(base + 33555456);       //  8.39 MB bf16 [B][S][KH][H]
    unsigned short* Vt   = (unsigned short*)(base + 41944064);       //  8.39 MB f16  [B][KH][H][S]
    unsigned short* xb   = (unsigned short*)(base + 50332672);       // 16.78 MB; reused as Ob
    unsigned short* qkvwT= (unsigned short*)(base + 67109888);       // 16.78 MB [4096][2048]
    unsigned short* owT  = (unsigned short*)(base + 83887104);       //  8.39 MB [2048][2048]
    unsigned short* Ob   = xb;

    // 1) fused prep: meta + cast + 4 transposes
    prep<<<Bc + 4096 + 4096 + 2048 + 2048 + 4096, 256, 0, stream>>>(
        x, q_w, k_w, v_w, o_w, seg, startind, meta, xb, qkvwT, owT);

    // 2) fused QKV projection: [4096 x 2048] @ [2048 x 4096]
    gemm_mfma<<<dim3(32, 32), 256, 0, stream>>>(xb, qkvwT, QKVh, Bc * Tc, 4096, Dc, 0);

    // 3) fused post: norm+rope, K-cache fill, V transpose (f16)
    post<<<24576 + 2048 + 2048, 256, 0, stream>>>(QKVh, Kall, Vt,
        q_norm_w, k_norm_w, seg, meta, cur_ptr, k_cache, v_cache);

    // 4) flash attention: 64-row tiles, 2-wave blocks, 4 blocks/CU
    flash_mfma<<<Bc * Nc * (Tc / 64), 128, 0, stream>>>(QKVh, Kall, Vt, seg, meta, cur_ptr, Ob);

    // 5) O projection -> fp32 out
    gemm_mfma<<<dim3(16, 32), 256, 0, stream>>>(Ob, owT, d_out, Bc * Tc, Dc, Nc * Hc, 1);
}

// Round 3
// 379.125 us; speedup vs baseline: 1.0991x; 1.0991x over previous
//
#include <hip/hip_runtime.h>
#include <hip/hip_fp16.h>
#include <climits>
#include <math.h>

#define Bc   2
#define Tc   2048
#define Dc   2048
#define Nc   16
#define KHc  8
#define Hc   128
#define Sc   2048

constexpr float EPSc   = 1e-6f;
constexpr float SCALE2 = 0.1275174477984469f;     // (1/sqrt(128)) * log2(e)

typedef short short8 __attribute__((ext_vector_type(8)));
typedef _Float16 half8 __attribute__((ext_vector_type(8)));
typedef __fp16 fp16x2 __attribute__((ext_vector_type(2)));
typedef float float4v __attribute__((ext_vector_type(4)));

union U16x8 { uint4 u; short8 s8; half8 h8; unsigned short us[8]; };
union H2U  { fp16x2 h; unsigned u; };
union S8H8 { short8 s; half8 h; };

__device__ __forceinline__ unsigned short f2bf(float f) {
    union { float f; unsigned u; } v; v.f = f;
    unsigned r = v.u + 0x7FFFu + ((v.u >> 16) & 1u);
    return (unsigned short)(r >> 16);
}
__device__ __forceinline__ float bf2f(unsigned short u) {
    union { unsigned u; float f; } v; v.u = ((unsigned)u) << 16;
    return v.f;
}

// ---------------------------------------------------------------------------
// prep: fused meta + x-cast + 4 weight transposes (12 launches -> 1)
// ---------------------------------------------------------------------------
__device__ __forceinline__ void tc_body(const float* __restrict__ in,
                                        unsigned short* __restrict__ out,
                                        int R, int C, int bx, int by, int tid,
                                        float tile[32][33])
{
    int c0 = bx * 32, r0 = by * 32;
#pragma unroll
    for (int i = 0; i < 4; ++i) {
        int row = (tid >> 5) + i * 8, col = tid & 31;
        tile[row][col] = in[(size_t)(r0 + row) * C + c0 + col];
    }
    __syncthreads();
#pragma unroll
    for (int i = 0; i < 4; ++i) {
        int rowo = (tid >> 5) + i * 8, colo = tid & 31;
        out[(size_t)(c0 + rowo) * R + r0 + colo] = f2bf(tile[colo][rowo]);
    }
}

__global__ __launch_bounds__(256) void prep(const float* __restrict__ x,
                                            const float* __restrict__ qw,
                                            const float* __restrict__ kw,
                                            const float* __restrict__ vw,
                                            const float* __restrict__ ow,
                                            const int* __restrict__ seg,
                                            const int* __restrict__ start_ind,
                                            int* __restrict__ meta,
                                            unsigned short* __restrict__ xb,
                                            unsigned short* __restrict__ qkvwT,
                                            unsigned short* __restrict__ owT)
{
    __shared__ float tile[32][33];
    __shared__ int s_max, s_amax, s_nz;
    int id = blockIdx.x;
    int tid = threadIdx.x;

    if (id < Bc) {   // meta
        int b = id;
        if (tid == 0) { s_max = INT_MIN; s_amax = Tc; s_nz = Tc; }
        __syncthreads();
        int lmax = INT_MIN;
        for (int t = tid; t < Tc; t += 256) lmax = max(lmax, seg[b * Tc + t]);
        atomicMax(&s_max, lmax);
        __syncthreads();
        int mv = s_max;
        int lamax = Tc, lnz = Tc;
        for (int t = tid; t < Tc; t += 256) {
            int v = seg[b * Tc + t];
            if (v == mv) lamax = min(lamax, t);
            if (v != 0)  lnz   = min(lnz, t);
        }
        atomicMin(&s_amax, lamax);
        atomicMin(&s_nz, lnz);
        __syncthreads();
        if (tid == 0) {
            meta[b] = s_amax;
            int st = start_ind[b];
            meta[Bc + b] = (st < 0) ? s_nz : st;
        }
        return;
    }
    id -= Bc;
    if (id < 4096) {   // cast x
        size_t base = ((size_t)id * 256 + tid) * 8;
        float4 a = *(const float4*)&x[base];
        float4 b = *(const float4*)&x[base + 4];
        U16x8 o;
        o.us[0] = f2bf(a.x); o.us[1] = f2bf(a.y); o.us[2] = f2bf(a.z); o.us[3] = f2bf(a.w);
        o.us[4] = f2bf(b.x); o.us[5] = f2bf(b.y); o.us[6] = f2bf(b.z); o.us[7] = f2bf(b.w);
        *(uint4*)&xb[base] = o.u;
        return;
    }
    id -= 4096;
    if (id < 4096) { tc_body(qw, qkvwT, 2048, 2048, id & 63, id >> 6, tid, tile); return; }
    id -= 4096;
    if (id < 2048) { tc_body(kw, qkvwT + (size_t)2048 * 2048, 2048, 1024, id & 31, id >> 5, tid, tile); return; }
    id -= 2048;
    if (id < 2048) { tc_body(vw, qkvwT + (size_t)3072 * 2048, 2048, 1024, id & 31, id >> 5, tid, tile); return; }
    id -= 2048;
    tc_body(ow, owT, 2048, 2048, id & 63, id >> 6, tid, tile);
}

// ---------------------------------------------------------------------------
// bf16 MFMA GEMM (m97 structure): C[M,N] = A[M,K] * BT[N,K]^T.
// ---------------------------------------------------------------------------
__global__ __launch_bounds__(256, 2) void gemm_mfma(const unsigned short* __restrict__ A,
                                                    const unsigned short* __restrict__ BT,
                                                    void* __restrict__ Cout,
                                                    int M, int N, int K, int out_fp32)
{
    __shared__ __align__(16) unsigned short As[128 * 32];
    __shared__ __align__(16) unsigned short Bs[128 * 32];
    int tid = threadIdx.x;
    int lane = tid & 63, w = tid >> 6;
    int quad = lane >> 4, l15 = lane & 15;
    int bm = blockIdx.y * 128, bn = blockIdx.x * 128;
    int wm = (w >> 1) * 64, wn = (w & 1) * 64;

    int srow = lane >> 2;
    int pl   = lane & 3;
    int sw   = (quad ^ ((l15 >> 1) & 3)) * 8;

    float4v acc[16];
#pragma unroll
    for (int i = 0; i < 16; ++i) acc[i] = (float4v)0.f;

    for (int k0 = 0; k0 < K; k0 += 32) {
        __syncthreads();
#pragma unroll
        for (int c = 0; c < 2; ++c) {
            int j = w * 2 + c;
            int row = j * 16 + srow;
            int pg = pl ^ ((row >> 1) & 3);
            __builtin_amdgcn_global_load_lds(
                (__attribute__((address_space(1))) void*)(A + (size_t)(bm + row) * K + k0 + pg * 8),
                (__attribute__((address_space(3))) void*)(As + j * 512), 16, 0, 0);
            __builtin_amdgcn_global_load_lds(
                (__attribute__((address_space(1))) void*)(BT + (size_t)(bn + row) * K + k0 + pg * 8),
                (__attribute__((address_space(3))) void*)(Bs + j * 512), 16, 0, 0);
        }
        __syncthreads();
        short8 af[4];
#pragma unroll
        for (int mi = 0; mi < 4; ++mi)
            af[mi] = *(const short8*)&As[(wm + mi * 16 + l15) * 32 + sw];
#pragma unroll
        for (int ni = 0; ni < 4; ++ni) {
            short8 bf = *(const short8*)&Bs[(wn + ni * 16 + l15) * 32 + sw];
#pragma unroll
            for (int mi = 0; mi < 4; ++mi)
                acc[mi * 4 + ni] = __builtin_amdgcn_mfma_f32_16x16x32_bf16(af[mi], bf, acc[mi * 4 + ni], 0, 0, 0);
        }
    }

#pragma unroll
    for (int mi = 0; mi < 4; ++mi)
#pragma unroll
        for (int ni = 0; ni < 4; ++ni)
#pragma unroll
            for (int reg = 0; reg < 4; ++reg) {
                int row = bm + wm + mi * 16 + quad * 4 + reg;
                int col = bn + wn + ni * 16 + l15;
                float v = acc[mi * 4 + ni][reg];
                if (out_fp32) ((float*)Cout)[(size_t)row * N + col] = v;
                else ((unsigned short*)Cout)[(size_t)row * N + col] = f2bf(v);
            }
}

// ---------------------------------------------------------------------------
// post: fused norm_rope (Q in-place, K -> Kall) + K-cache fill + V transpose
// ---------------------------------------------------------------------------
__global__ __launch_bounds__(256) void post(unsigned short* __restrict__ QKVh,
                                            unsigned short* __restrict__ Kall,
                                            unsigned short* __restrict__ Vt,
                                            const float* __restrict__ qw,
                                            const float* __restrict__ kw,
                                            const int* __restrict__ seg,
                                            const int* __restrict__ meta,
                                            const int* __restrict__ cur_ptr,
                                            const float* __restrict__ kc,
                                            const float* __restrict__ vc)
{
    int id = blockIdx.x;
    int tid = threadIdx.x;
    int cur = cur_ptr[0];

    if (id < 24576) {   // norm + rope
        int rowid = id * 4 + (tid >> 6);
        int lane = tid & 63;
        int hh = rowid % 24;
        int bt = rowid / 24;
        int t = bt & (Tc - 1);
        int b = bt >> 11;

        const unsigned short* in;
        unsigned short* out;
        const float* wt;
        if (hh < 16) {
            unsigned short* p = QKVh + (size_t)bt * 4096 + hh * Hc;
            in = p; out = p; wt = qw;
        } else {
            int kh = hh - 16;
            in = QKVh + (size_t)bt * 4096 + 2048 + kh * Hc;
            out = Kall + (((size_t)b * Sc + cur + t) * KHc + kh) * Hc;
            wt = kw;
        }
        float v1 = bf2f(in[lane]), v2 = bf2f(in[lane + 64]);
        float ssq = v1 * v1 + v2 * v2;
#pragma unroll
        for (int off = 1; off < 64; off <<= 1) ssq += __shfl_xor(ssq, off);
        float rinv = rsqrtf(ssq * (1.0f / Hc) + EPSc);

        int sg = seg[bt];
        long long pos = (sg != 0) ? (long long)(t - meta[b]) : (long long)(1 << 30);
        float posf = (float)(pos + (long long)cur);
        float inv_freq = exp2f(-(float)lane * (19.931568569324174f / 64.0f));
        float s, c;
        sincosf(posf * inv_freq, &s, &c);

        float n1 = wt[lane] * v1 * rinv;
        float n2 = wt[lane + 64] * v2 * rinv;
        out[lane]      = f2bf(n1 * c - n2 * s);
        out[lane + 64] = f2bf(n2 * c + n1 * s);
        return;
    }
    id -= 24576;
    if (id < 2048) {   // K cache fill
        size_t base = ((size_t)id * 256 + tid) * 8;
        int s = (int)((base >> 10) & (Sc - 1));
        if (s >= cur && s < cur + Tc) return;
        float4 a = *(const float4*)&kc[base];
        float4 b = *(const float4*)&kc[base + 4];
        U16x8 o;
        o.us[0] = f2bf(a.x); o.us[1] = f2bf(a.y); o.us[2] = f2bf(a.z); o.us[3] = f2bf(a.w);
        o.us[4] = f2bf(b.x); o.us[5] = f2bf(b.y); o.us[6] = f2bf(b.z); o.us[7] = f2bf(b.w);
        *(uint4*)&Kall[base] = o.u;
        return;
    }
    id -= 2048;
    {   // V transpose -> f16
        int gid = id * 256 + tid;
        int h  = gid & 127;
        int s8 = ((gid >> 7) & 255) * 8;
        int kh = (gid >> 15) & 7;
        int b  = gid >> 18;
        int curT = cur + Tc;
        unsigned short tmp[8];
#pragma unroll
        for (int e = 0; e < 8; ++e) {
            int s = s8 + e;
            float f;
            if (s >= cur && s < curT)
                f = bf2f(QKVh[(size_t)(b * Tc + (s - cur)) * 4096 + 3072 + kh * Hc + h]);
            else
                f = vc[((size_t)(b * Sc + s) * KHc + kh) * Hc + h];
            tmp[e] = __half_as_ushort(__float2half(f));
        }
        *(uint4*)&Vt[(((size_t)b * KHc + kh) * Hc + h) * Sc + s8] = *(uint4*)tmp;
    }
}

// ---------------------------------------------------------------------------
// MFMA flash attention, S^T formulation — 8-wave version:
//   Same 128-row q-tiles / 512-block grid as the proven R0 kernel, but
//   8 waves per block (512 threads), each wave owning 16 q-rows.
//   Rationale (R1/R2 post-mortems): staging latency is hidden already;
//   the cost is intra-wave dependency stalls at 1 wave/SIMD. 8-wave
//   blocks give 2 waves/SIMD even when a block runs solo (tail), 4/SIMD
//   when 2 blocks/CU co-run. Per-wave work halves (16+16 MFMA, 2+2
//   global_load_lds per chunk); block totals unchanged.
//   LDS = Ks 16K + Vs 16K + Ps 16K (64-stride XOR-swizzled) = 48 KB.
// ---------------------------------------------------------------------------
__global__ __launch_bounds__(512, 4) void flash_mfma(const unsigned short* __restrict__ Qb,
                                                     const unsigned short* __restrict__ Kall,
                                                     const unsigned short* __restrict__ Vt,
                                                     const int* __restrict__ seg,
                                                     const int* __restrict__ meta,
                                                     const int* __restrict__ cur_ptr,
                                                     unsigned short* __restrict__ Ob)
{
    __shared__ __align__(16) unsigned short Ks[64 * 128];   // bf16 [s][h], swizzled
    __shared__ __align__(16) unsigned short Vs[128 * 64];   // f16  [h][s], swizzled
    __shared__ __align__(16) unsigned short Ps[128 * 64];   // f16  [q][s], XOR-swizzled

    int tid = threadIdx.x;
    int lane = tid & 63, w = tid >> 6;          // w in 0..7
    int quad = lane >> 4, l15 = lane & 15;
    int bid = blockIdx.x;
    int raw = bid & 15;
    int n  = (bid >> 4) & 15;
    int b  = bid >> 8;
    int qt = (b == 0) ? raw : (15 - raw);
    int kh = n >> 1;
    int cur = cur_ptr[0];
    int startb = meta[Bc + b];
    int curT = cur + Tc;
    int t0 = qt * 128 + w * 16;                 // this wave's 16 q-rows

    // Q fragments (B-operand layout == A layout: l15 -> q, quad*8+j -> h)
    short8 qf[4];
#pragma unroll
    for (int ks = 0; ks < 4; ++ks) {
        int row = t0 + l15;
        U16x8 uq;
        uq.u = *(const uint4*)&Qb[(size_t)(b * Tc + row) * 4096 + n * Hc + ks * 32 + quad * 8];
        qf[ks] = uq.s8;
    }

    // per-lane mask metadata (q = l15-indexed)
    int trow0 = t0 + l15;
    int sg0 = seg[b * Tc + trow0];
    int cls = (sg0 == 0) ? 0 : ((sg0 == 1) ? 1 : 2);
    int ct  = cur + trow0;
    unsigned long long mball = __ballot(cls == 1);
    bool allseg1 = (mball == 0xFFFFFFFFFFFFFFFFull);

    float lsum = 0.f;
    float4v oT[8];   // [htile]
#pragma unroll
    for (int i = 0; i < 8; ++i) oT[i] = (float4v)0.f;

    int s_end = min(Sc, cur + qt * 128 + 128);
    int nch = (s_end + 63) >> 6;

    // staging geometry (per wave: 2 K + 2 V global_load_lds per chunk)
    const size_t kstride = (size_t)KHc * Hc;
    const unsigned short* kptr[2];
    unsigned short* kdst[2];
#pragma unroll
    for (int i = 0; i < 2; ++i) {
        int j = w * 2 + i;                      // 0..15
        int row = j * 4 + (lane >> 4);          // 0..63
        int pl = lane & 15;
        int pg = pl ^ ((row >> 1) & 7);
        kptr[i] = Kall + (size_t)b * Sc * kstride + (size_t)row * kstride + kh * Hc + pg * 8;
        kdst[i] = Ks + j * 512;
    }
    const unsigned short* vptr[2];
    unsigned short* vdst[2];
#pragma unroll
    for (int i = 0; i < 2; ++i) {
        int j = w * 2 + i;                      // 0..15
        int h = j * 8 + (lane >> 3);            // 0..127
        int pl = lane & 7;
        int pg = pl ^ ((h >> 1) & 7);
        vptr[i] = Vt + ((size_t)b * KHc + kh) * (size_t)Hc * Sc + (size_t)h * Sc + pg * 8;
        vdst[i] = Vs + j * 512;
    }
    int sw3 = (l15 >> 1) & 7;
    int sw8 = l15 & 7;                          // Ps 16B-slot swizzle key (== row&7)
    unsigned short* psrow = Ps + (w * 16 + l15) * 64;   // this wave's q-row

    for (int c = 0; c < nch; ++c) {
        int s0 = c * 64;
#pragma unroll
        for (int i = 0; i < 2; ++i) {
            __builtin_amdgcn_global_load_lds(
                (__attribute__((address_space(1))) void*)(kptr[i] + (size_t)s0 * kstride),
                (__attribute__((address_space(3))) void*)kdst[i], 16, 0, 0);
            __builtin_amdgcn_global_load_lds(
                (__attribute__((address_space(1))) void*)(vptr[i] + s0),
                (__attribute__((address_space(3))) void*)vdst[i], 16, 0, 0);
        }
        __syncthreads();

        // S^T = K·Q^T : st[stile], row=s, col=q
        float4v st[4];
#pragma unroll
        for (int i = 0; i < 4; ++i) st[i] = (float4v)0.f;
        __builtin_amdgcn_s_setprio(1);
#pragma unroll
        for (int ks = 0; ks < 4; ++ks) {
#pragma unroll
            for (int stile = 0; stile < 4; ++stile) {
                short8 kf = *(const short8*)&Ks[(stile * 16 + l15) * 128 + ((ks * 4 + quad) ^ sw3) * 8];
                st[stile] = __builtin_amdgcn_mfma_f32_16x16x32_bf16(kf, qf[ks], st[stile], 0, 0, 0);
            }
        }
        __builtin_amdgcn_s_setprio(0);

        bool fullok = allseg1 && (s0 >= startb) && (s0 + 63 <= cur + t0) && (s0 + 63 < curT);

        // softmax: p = exp2(score*SCALE2); pack 4 s-consecutive f16 -> uint2 store
#pragma unroll
        for (int stile = 0; stile < 4; ++stile) {
            float p0, p1, p2, p3;
            if (fullok) {
                p0 = exp2f(st[stile][0] * SCALE2);
                p1 = exp2f(st[stile][1] * SCALE2);
                p2 = exp2f(st[stile][2] * SCALE2);
                p3 = exp2f(st[stile][3] * SCALE2);
            } else {
                float pp[4];
#pragma unroll
                for (int reg = 0; reg < 4; ++reg) {
                    int s = s0 + stile * 16 + quad * 4 + reg;
                    int kvseg = (s >= startb && s < curT) ? 1 : 0;
                    bool ok = (s <= ct) && (cls == kvseg);
                    pp[reg] = exp2f(ok ? st[stile][reg] * SCALE2 : -1e30f);
                }
                p0 = pp[0]; p1 = pp[1]; p2 = pp[2]; p3 = pp[3];
            }
            lsum += (p0 + p1) + (p2 + p3);
            H2U a, d;
            a.h = __builtin_amdgcn_cvt_pkrtz(p0, p1);
            d.h = __builtin_amdgcn_cvt_pkrtz(p2, p3);
            uint2 pk; pk.x = a.u; pk.y = d.u;
            // 16B slot = (stile*2 + (quad>>1)) ^ sw8 ; uint2 in half (quad&1)
            *(uint2*)&psrow[(((stile * 2 + (quad >> 1)) ^ sw8) << 3) + (quad & 1) * 4] = pk;
        }

        // O^T += V^T · P^T   (A = Vs f16, B = Ps f16) — own wave's Ps row only
        __builtin_amdgcn_s_setprio(1);
#pragma unroll
        for (int kk = 0; kk < 2; ++kk) {
            S8H8 pf;
            pf.s = *(const short8*)&psrow[((kk * 4 + quad) ^ sw8) << 3];
#pragma unroll
            for (int htile = 0; htile < 8; ++htile) {
                S8H8 vf;
                vf.s = *(const short8*)&Vs[(htile * 16 + l15) * 64 + ((kk * 4 + quad) ^ sw3) * 8];
                oT[htile] = __builtin_amdgcn_mfma_f32_16x16x32_f16(vf.h, pf.h, oT[htile], 0, 0, 0);
            }
        }
        __builtin_amdgcn_s_setprio(0);

        __syncthreads();   // WAR: next staging overwrites Ks/Vs
    }

    // l: sum across the 4 quads holding the same q (xor 16, 32)
    float l = lsum;
    l += __shfl_xor(l, 16);
    l += __shfl_xor(l, 32);
    float linv = (l > 0.f) ? (1.0f / l) : 0.f;

    // epilogue: O^T col=q(l15), row=h(quad*4+reg) -> packed bf16 stores
    {
        int trow = t0 + l15;
        size_t base = ((size_t)(b * Tc + trow) * Nc + n) * Hc;
#pragma unroll
        for (int htile = 0; htile < 8; ++htile) {
            float4v v = oT[htile];
            unsigned short r0 = f2bf(v[0] * linv);
            unsigned short r1 = f2bf(v[1] * linv);
            unsigned short r2 = f2bf(v[2] * linv);
            unsigned short r3 = f2bf(v[3] * linv);
            uint2 pk;
            pk.x = (unsigned)r0 | ((unsigned)r1 << 16);
            pk.y = (unsigned)r2 | ((unsigned)r3 << 16);
            *(uint2*)&Ob[base + htile * 16 + quad * 4] = pk;
        }
    }
}

// ---------------------------------------------------------------------------
extern "C" void kernel_launch(void* const* d_in, const int* in_sizes, int n_in,
                              void* d_out, int out_size, void* d_ws, size_t ws_size,
                              hipStream_t stream)
{
    const float* x        = (const float*)d_in[0];
    const float* q_w      = (const float*)d_in[1];
    const float* k_w      = (const float*)d_in[2];
    const float* v_w      = (const float*)d_in[3];
    const float* o_w      = (const float*)d_in[4];
    const float* q_norm_w = (const float*)d_in[5];
    const float* k_norm_w = (const float*)d_in[6];
    const float* k_cache  = (const float*)d_in[7];
    const float* v_cache  = (const float*)d_in[8];
    const int*   seg      = (const int*)d_in[9];
    const int*   startind = (const int*)d_in[10];
    const int*   cur_ptr  = (const int*)d_in[11];
    (void)in_sizes; (void)n_in; (void)out_size; (void)ws_size;

    char* base = (char*)d_ws;
    int* meta = (int*)base;                                          //      1024 B
    unsigned short* QKVh = (unsigned short*)(base + 1024);           // 33.55 MB [4096][4096]
    unsigned short* Kall = (unsigned short*)(base + 33555456);       //  8.39 MB bf16 [B][S][KH][H]
    unsigned short* Vt   = (unsigned short*)(base + 41944064);       //  8.39 MB f16  [B][KH][H][S]
    unsigned short* xb   = (unsigned short*)(base + 50332672);       // 16.78 MB; reused as Ob
    unsigned short* qkvwT= (unsigned short*)(base + 67109888);       // 16.78 MB [4096][2048]
    unsigned short* owT  = (unsigned short*)(base + 83887104);       //  8.39 MB [2048][2048]
    unsigned short* Ob   = xb;

    // 1) fused prep: meta + cast + 4 transposes
    prep<<<Bc + 4096 + 4096 + 2048 + 2048 + 4096, 256, 0, stream>>>(
        x, q_w, k_w, v_w, o_w, seg, startind, meta, xb, qkvwT, owT);

    // 2) fused QKV projection: [4096 x 2048] @ [2048 x 4096]
    gemm_mfma<<<dim3(32, 32), 256, 0, stream>>>(xb, qkvwT, QKVh, Bc * Tc, 4096, Dc, 0);

    // 3) fused post: norm+rope, K-cache fill, V transpose (f16)
    post<<<24576 + 2048 + 2048, 256, 0, stream>>>(QKVh, Kall, Vt,
        q_norm_w, k_norm_w, seg, meta, cur_ptr, k_cache, v_cache);

    // 4) flash attention: 128-row tiles, 8-wave blocks (2 waves/SIMD min)
    flash_mfma<<<Bc * Nc * (Tc / 128), 512, 0, stream>>>(QKVh, Kall, Vt, seg, meta, cur_ptr, Ob);

    // 5) O projection -> fp32 out
    gemm_mfma<<<dim3(16, 32), 256, 0, stream>>>(Ob, owT, d_out, Bc * Tc, Dc, Nc * Hc, 1);
}